// Round 10
// baseline (146.235 us; speedup 1.0000x reference)
//
#include <hip/hip_runtime.h>
#include <math.h>

#define NT_ 365
#define NS_ 1024
#define NH_ 64
#define NG_ 32
#define NW_ 514        // NH*8 + 2
#define SEG_ 96        // segment stride: waves 0-2 own 96 steps, wave 3 owns 77
#define CH_ 16         // full-phase chunk length (ytile rows)
#define YPAD_ 68       // row stride (floats): 16B-aligned rows, conflict-free
#define NTPAD_ 384     // met buffer, padded past 365 with zeros

__device__ __forceinline__ float sigmoidf(float v) {
  return 1.0f / (1.0f + expf(-v));
}

// met = (Ps, Pl, relu(Ta), E); relu folded here since gm > 0
__device__ __forceinline__ float4 compute_met(float4 xv) {
  const float P = xv.x, E = xv.y, T1 = xv.z, T2 = xv.w;
  const float Ta = (T1 + T2) * 0.5f;
  float rP;
  if (T2 <= 0.0f) {
    rP = 0.0f;
  } else if (T1 >= 0.0f) {
    rP = 1.0f;
  } else {
    float r = (T1 + T2) / (T2 - T1);
    r = fminf(fmaxf(r, -0.999999f), 0.999999f);
    rP = 1.0f - acosf(r) * (1.0f / 3.1415f);
  }
  float4 m;
  m.x = (1.0f - rP) * P;   // Ps
  m.y = rP * P;            // Pl
  m.z = fmaxf(Ta, 0.0f);   // relu(Ta)
  m.w = E;
  return m;
}

// ---- segmented scan: 1 block = 1 site, 4 waves = 4 time segments ----------
// Wave w re-scans steps [0, 96w) in a light state-only loop (redundant work),
// then produces outputs for its own segment. 1024 blocks -> 4 blocks/CU ->
// 4 waves/SIMD on ALL SIMDs: the measured single-wave issue cadence (~9
// cyc/instr, R4/R7/R8) is filled by TLP (mechanism validated by R5) without
// idling half the machine (R5's failure mode).
__global__ __launch_bounds__(256, 4) void waternet_scan(
    const float* __restrict__ x,     // [NT, NS, 4]
    const float* __restrict__ xc,    // [NS, NG]
    const float* __restrict__ fc_w,  // [NW, NG]
    const float* __restrict__ fc_b,  // [NW]
    float* __restrict__ out)         // [NT, NS]
{
  __shared__ float4 smet[NTPAD_];            // 6 KB: met for all t (shared)
  __shared__ float  ytile[4][CH_ * YPAD_];   // 17.4 KB: per-wave y transpose

  const int tid  = threadIdx.x;
  const int lane = tid & 63;
  const int wv   = tid >> 6;              // segment index 0..3
  const int site = blockIdx.x;            // scalar (SGPR)
  const float4* xp = (const float4*)x;

  // ---- issue met x-loads first; consumed after the GEMM (latency hidden)
  const float4 xv1 = xp[tid * NS_ + site];            // t = tid (0..255)
  const int    t2  = 256 + tid;
  float4 xv2 = make_float4(0.0f, 0.0f, 0.0f, 0.0f);
  if (t2 < NT_) xv2 = xp[t2 * NS_ + site];

  // ---- gate GEMM (redundant per wave): w[site,j] = xc[site,:].fc_w[j,:]+b
  float acc[8];
#pragma unroll
  for (int k = 0; k < 8; ++k) acc[k] = fc_b[k * NH_ + lane];
  float accq = fc_b[NW_ - 1];

  const float4* xcq = (const float4*)(xc + site * NG_);
  const float4* wq4 = (const float4*)fc_w;
#pragma unroll
  for (int g4 = 0; g4 < NG_ / 4; ++g4) {
    const float4 xv = xcq[g4];
#pragma unroll
    for (int k = 0; k < 8; ++k) {
      const float4 w = wq4[(k * NH_ + lane) * (NG_ / 4) + g4];
      acc[k] = fmaf(xv.x, w.x, acc[k]);
      acc[k] = fmaf(xv.y, w.y, acc[k]);
      acc[k] = fmaf(xv.z, w.z, acc[k]);
      acc[k] = fmaf(xv.w, w.w, acc[k]);
    }
    {
      const float4 w = wq4[(NW_ - 1) * (NG_ / 4) + g4];
      accq = fmaf(xv.x, w.x, accq);
      accq = fmaf(xv.y, w.y, accq);
      accq = fmaf(xv.z, w.z, accq);
      accq = fmaf(xv.w, w.w, accq);
    }
  }

  // ---- gates (per-lane = per hidden unit)
  const float gm = expf(acc[0]) + 1.0f;
  const float ge = sigmoidf(acc[1]) * 2.0f;
  const float go = sigmoidf(acc[2]);
  const float gl = expf(acc[3] * 2.0f);
  float mx = acc[4];
#pragma unroll
  for (int mm = 32; mm >= 1; mm >>= 1) mx = fmaxf(mx, __shfl_xor(mx, mm, 64));
  const float ex = expf(acc[4] - mx);
  float sm = ex;
#pragma unroll
  for (int mm = 32; mm >= 1; mm >>= 1) sm += __shfl_xor(sm, mm, 64);
  const float ga = ex / sm;
  const float gb = sigmoidf(acc[5]);
  const float kb = sigmoidf(acc[6]) * 0.1f;
  const float gi = sigmoidf(acc[7]);
  const float qb = fmaxf(accq, 0.0f) * (1.0f / NH_);
  const float kb1m = 1.0f - kb;                 // G0' = G*(1-kb)
  const float nge  = -ge;
  const float gq1  = go * (1.0f - gb) - 1.0f;   // y = ga*(H + M*gq1 + G*kb)

  // ---- stage met to LDS (thread t -> timestep t; zeros past 365)
  smet[tid] = compute_met(xv1);
  if (t2 < NTPAD_) {
    float4 m2 = make_float4(0.0f, 0.0f, 0.0f, 0.0f);
    if (t2 < NT_) m2 = compute_met(xv2);
    smet[t2] = m2;
  }
  __syncthreads();

  // ---- scan state
  float S0 = 0.0f, H0 = 0.0f, G0 = 0.0f;

  // ---- light pre-scan: steps [0, 96*wv), state only (~15 instr/step)
  const int lim = wv * SEG_;                 // 0, 96, 192, 288 (all %8 == 0)
  for (int t0 = 0; t0 < lim; t0 += 8) {
    float4 mb[8];
#pragma unroll
    for (int u = 0; u < 8; ++u) mb[u] = smet[t0 + u];
#pragma unroll
    for (int u = 0; u < 8; ++u) {
      const float4 mt = mb[u];
      const float melt = mt.z * gm;
      const float Sm   = fminf(S0, melt);
      const float base = H0 + Sm;
      S0 = (S0 - Sm) + mt.x;
      const float H = fmaxf(fmaf(mt.w, nge, fmaf(mt.y, gi, base)), 0.0f);
      const float M = fminf(H, gl);
      const float Q2a = M * go;
      H0 = fminf(H - Q2a, gl);
      G0 = fmaf(Q2a, gb, G0) * kb1m;
    }
  }

  // ---- full phase: wave w owns steps [96w, 96w+96) (wave 3: 80, masked)
  const int segbase = lim;
  const int nch = (wv == 3) ? 5 : 6;         // wave-uniform trip count
  float*       yw = &ytile[wv][lane];        // step j writes yw[j*YPAD_]
  const float* yr = &ytile[wv][lane * YPAD_];

  for (int cc = 0; cc < nch; ++cc) {
    const float4* mp = &smet[segbase + cc * CH_];
#pragma unroll
    for (int j = 0; j < CH_; ++j) {
      const float4 mt = mp[j];               // ds_read_b128, imm offset
      const float melt = mt.z * gm;
      const float Sm   = fminf(S0, melt);
      const float base = H0 + Sm;
      S0 = (S0 - Sm) + mt.x;
      const float H = fmaxf(fmaf(mt.w, nge, fmaf(mt.y, gi, base)), 0.0f);
      const float M = fminf(H, gl);
      const float Q2a = M * go;
      H0 = fminf(H - Q2a, gl);
      const float G = fmaf(Q2a, gb, G0);
      G0 = G * kb1m;
      yw[j * YPAD_] = fmaf(G, kb, fmaf(M, gq1, H)) * ga;  // ds_write_b32
    }
    // transposed reduce: lane j (<16) sums row j via 16 b128 reads
    if (lane < CH_) {
      const float4* yv = (const float4*)yr;  // row is 16B-aligned (YPAD=68)
      float4 r0 = yv[0], r1 = yv[1], r2 = yv[2], r3 = yv[3];
#pragma unroll
      for (int h = 4; h < 16; h += 4) {
        r0 += yv[h + 0];
        r1 += yv[h + 1];
        r2 += yv[h + 2];
        r3 += yv[h + 3];
      }
      const float4 rs = (r0 + r1) + (r2 + r3);
      const float tot = (rs.x + rs.y) + (rs.z + rs.w);
      const int t_out = segbase + cc * CH_ + lane;
      if (t_out < NT_) out[t_out * NS_ + site] = tot + qb;
    }
  }
}

extern "C" void kernel_launch(void* const* d_in, const int* in_sizes, int n_in,
                              void* d_out, int out_size, void* d_ws, size_t ws_size,
                              hipStream_t stream) {
  const float* x    = (const float*)d_in[0];
  const float* xc   = (const float*)d_in[1];
  const float* fc_w = (const float*)d_in[2];
  const float* fc_b = (const float*)d_in[3];
  float* out = (float*)d_out;

  // 1 block = 1 site (4 segment-waves); 1024 blocks -> 4 blocks/CU ->
  // 4 waves/SIMD machine-wide.
  hipLaunchKernelGGL(waternet_scan, dim3(NS_), dim3(256), 0, stream,
                     x, xc, fc_w, fc_b, out);
}